// Round 1
// baseline (2573.141 us; speedup 1.0000x reference)
//
#include <hip/hip_runtime.h>
#include <math.h>

// Problem constants
#define LSEQ 1024
#define DMODEL 1024
#define NBATCH 4
#define NP 64      // B*H "batches" after the raw reshape
#define DH 64      // per-"head" dim after the raw reshape
#define NROWS 4096 // B*L

// workspace offsets (in floats). CTX aliases Q, PROJ aliases K (lifetimes disjoint).
#define OFF_Q     0u
#define OFF_K     4194304u
#define OFF_V     8388608u
#define OFF_RS    12582912u   // 64*1024 row sums
#define OFF_LOGRS 12648448u
#define OFF_VSUM  12713984u   // 64*64 column sums of V per p
#define OFF_CTX   OFF_Q
#define OFF_PROJ  OFF_K

// ---------------------------------------------------------------------------
// conv_causal + bias + exact GELU.  y[b,l,o] = gelu(sum_{kk,i} w[o,i,kk] *
// x[b,(l+kk-2)&1023,i] + bias[o]).  Tiled 64x64 GEMM, K = 3*1024 (3 taps).
// LDS layout [k][row] / [k][col] so float4 reads are conflict-light.
// ---------------------------------------------------------------------------
__global__ __launch_bounds__(256) void conv_gelu_kernel(
    const float* __restrict__ x, const float* __restrict__ w,
    const float* __restrict__ bias, float* __restrict__ y) {
  __shared__ float As[32][68];
  __shared__ float Ws[32][68];
  const int t = threadIdx.x;
  const int r0 = blockIdx.x * 64;   // output row tile (rows = b*1024 + l)
  const int o0 = blockIdx.y * 64;   // output col tile
  const int b  = r0 >> 10;
  const int l0 = r0 & 1023;
  const int tr = t >> 4, tc = t & 15;
  const float* xb = x + (size_t)b * (LSEQ * DMODEL);
  float acc[4][4] = {};

  for (int kk = 0; kk < 3; ++kk) {
    for (int i0 = 0; i0 < DMODEL; i0 += 32) {
      #pragma unroll
      for (int u = 0; u < 8; ++u) {
        int idx = t + u * 256;
        int k = idx & 31, rr = idx >> 5;
        int l = (l0 + rr + kk - 2) & 1023;   // wrap pad
        As[k][rr] = xb[l * DMODEL + i0 + k];
      }
      #pragma unroll
      for (int u = 0; u < 8; ++u) {
        int idx = t + u * 256;
        int k = idx & 31, oo = idx >> 5;
        Ws[k][oo] = w[(size_t)(o0 + oo) * 3072 + (i0 + k) * 3 + kk];
      }
      __syncthreads();
      #pragma unroll
      for (int k = 0; k < 32; ++k) {
        const float4 av = *(const float4*)&As[k][4 * tr];
        const float4 bv = *(const float4*)&Ws[k][4 * tc];
        float a[4] = {av.x, av.y, av.z, av.w};
        float bb[4] = {bv.x, bv.y, bv.z, bv.w};
        #pragma unroll
        for (int i = 0; i < 4; ++i)
          #pragma unroll
          for (int j = 0; j < 4; ++j)
            acc[i][j] = fmaf(a[i], bb[j], acc[i][j]);
      }
      __syncthreads();
    }
  }
  #pragma unroll
  for (int i = 0; i < 4; ++i) {
    int row = r0 + tr * 4 + i;
    float4 o4;
    float* po = (float*)&o4;
    #pragma unroll
    for (int j = 0; j < 4; ++j) {
      int col = o0 + tc * 4 + j;
      float vv = acc[i][j] + bias[col];
      po[j] = 0.5f * vv * (1.0f + erff(vv * 0.70710678118654752440f));
    }
    *(float4*)&y[(size_t)row * DMODEL + (o0 + tc * 4)] = o4;
  }
}

// ---------------------------------------------------------------------------
// per-p column sums of V: vsum[p][dd] = sum_j V[p,j,dd]
// ---------------------------------------------------------------------------
__global__ __launch_bounds__(256) void vsum_kernel(
    const float* __restrict__ V, float* __restrict__ vsum) {
  __shared__ float red[4][64];
  const int p = blockIdx.x;
  const int t = threadIdx.x;
  const int dd = t & 63, jq = t >> 6;
  const float* vp = V + (size_t)p * 65536;
  float s = 0.f;
  #pragma unroll 8
  for (int j = jq * 256; j < jq * 256 + 256; ++j) s += vp[j * 64 + dd];
  red[jq][dd] = s;
  __syncthreads();
  if (jq == 0) vsum[p * 64 + dd] = red[0][dd] + red[1][dd] + red[2][dd] + red[3][dd];
}

// ---------------------------------------------------------------------------
// Attention main pass. Block = (p, 32 q-rows). Writes log(c) to attn area,
// accumulates rowsum(c) and ctx_part = log(c) @ V.
// thread t: r = t>>3 (row in tile), g = t&7.  S cols j = g + 8u.
// ---------------------------------------------------------------------------
__global__ __launch_bounds__(256) void attn_main_kernel(
    const float* __restrict__ Q, const float* __restrict__ K,
    const float* __restrict__ V, float* __restrict__ attn_out,
    float* __restrict__ ctx_out, float* __restrict__ rs_out) {
  __shared__ float qs[32][68];
  __shared__ float ks[64][68];
  __shared__ float vs[64][68];
  __shared__ float ls[32][65];
  const int t = threadIdx.x;
  const int p = blockIdx.x;
  const int rt = blockIdx.y;
  const int r = t >> 3, g = t & 7;
  const float* qp = Q + (size_t)p * 65536 + (size_t)rt * 2048;
  const float* kp = K + (size_t)p * 65536;
  const float* vp = V + (size_t)p * 65536;
  float* ao = attn_out + (size_t)p * 1048576 + (size_t)rt * 32768;

  #pragma unroll
  for (int u = 0; u < 8; ++u) {
    int idx = t + u * 256;
    qs[idx >> 6][idx & 63] = qp[idx];
  }
  float ctx[8] = {0.f, 0.f, 0.f, 0.f, 0.f, 0.f, 0.f, 0.f};
  float rowsum = 0.f;
  __syncthreads();

  float4 qreg[16];
  #pragma unroll
  for (int q4 = 0; q4 < 16; ++q4) qreg[q4] = *(const float4*)&qs[r][4 * q4];

  for (int k0 = 0; k0 < LSEQ; k0 += 64) {
    #pragma unroll
    for (int u = 0; u < 16; ++u) {
      int idx = t + u * 256;
      int jj = idx >> 6, ii = idx & 63;
      ks[jj][ii] = kp[k0 * 64 + idx];
      vs[jj][ii] = vp[k0 * 64 + idx];
    }
    __syncthreads();
    // S phase: 8 columns per thread
    #pragma unroll
    for (int u = 0; u < 8; ++u) {
      int j = g + 8 * u;
      const float4* krow = (const float4*)&ks[j][0];
      float sum = 0.f;
      #pragma unroll
      for (int q4 = 0; q4 < 16; ++q4) {
        float4 kv = krow[q4];
        sum += qreg[q4].x * kv.x + qreg[q4].y * kv.y +
               qreg[q4].z * kv.z + qreg[q4].w * kv.w;
      }
      float c = fmaxf(0.5f * sum, 0.1f);  // scale then clamp
      rowsum += c;
      ls[r][j] = logf(c);
    }
    __syncthreads();
    // coalesced global write of log(c)
    #pragma unroll
    for (int u = 0; u < 8; ++u) {
      int idx = t + u * 256;
      int rr = idx >> 6, jj = idx & 63;
      ao[(size_t)rr * 1024 + k0 + jj] = ls[rr][jj];
    }
    // PV: ctx[r][8g..8g+7] += sum_j ls[r][j] * vs[j][...]
    #pragma unroll
    for (int jj = 0; jj < 64; ++jj) {
      float a = ls[r][jj];
      float4 v0 = *(const float4*)&vs[jj][8 * g];
      float4 v1 = *(const float4*)&vs[jj][8 * g + 4];
      ctx[0] = fmaf(a, v0.x, ctx[0]); ctx[1] = fmaf(a, v0.y, ctx[1]);
      ctx[2] = fmaf(a, v0.z, ctx[2]); ctx[3] = fmaf(a, v0.w, ctx[3]);
      ctx[4] = fmaf(a, v1.x, ctx[4]); ctx[5] = fmaf(a, v1.y, ctx[5]);
      ctx[6] = fmaf(a, v1.z, ctx[6]); ctx[7] = fmaf(a, v1.w, ctx[7]);
    }
    __syncthreads();
  }
  // reduce rowsum over the 8 g-lanes sharing row r (consecutive lanes)
  rowsum += __shfl_xor(rowsum, 1);
  rowsum += __shfl_xor(rowsum, 2);
  rowsum += __shfl_xor(rowsum, 4);
  if (g == 0) rs_out[p * 1024 + rt * 32 + r] = rowsum;
  #pragma unroll
  for (int u = 0; u < 8; ++u)
    ctx_out[(size_t)p * 65536 + (size_t)(rt * 32 + r) * 64 + 8 * g + u] = ctx[u];
}

__global__ __launch_bounds__(256) void logrs_kernel(
    const float* __restrict__ rs, float* __restrict__ logrs) {
  int i = blockIdx.x * 256 + threadIdx.x;
  logrs[i] = logf(rs[i]);
}

// attn[p,i,j] -= log(rowsum[p,i])   (float4 grid-stride over 64M floats)
__global__ __launch_bounds__(256) void fixup_attn_kernel(
    float* __restrict__ attn, const float* __restrict__ logrs) {
  size_t i = (size_t)blockIdx.x * 256 + threadIdx.x;
  const size_t stride = (size_t)gridDim.x * 256;
  float4* a4 = (float4*)attn;
  const size_t n4 = 16777216;
  for (; i < n4; i += stride) {
    float lr = logrs[i >> 8];
    float4 v = a4[i];
    v.x -= lr; v.y -= lr; v.z -= lr; v.w -= lr;
    a4[i] = v;
  }
}

// ctx[p,i,dd] -= log(rowsum[p,i]) * vsum[p,dd]
__global__ __launch_bounds__(256) void fixup_ctx_kernel(
    float* __restrict__ ctx, const float* __restrict__ logrs,
    const float* __restrict__ vsum) {
  int i = blockIdx.x * 256 + threadIdx.x;  // over 1M float4s
  float lr = logrs[i >> 4];
  float4 vs4 = ((const float4*)vsum)[((i >> 14) << 4) | (i & 15)];
  float4 v = ((float4*)ctx)[i];
  v.x -= lr * vs4.x; v.y -= lr * vs4.y; v.z -= lr * vs4.z; v.w -= lr * vs4.w;
  ((float4*)ctx)[i] = v;
}

// out-projection GEMM: y[r,o] = sum_d A[r,d]*wf[o,d] + bf[o]
__global__ __launch_bounds__(256) void proj_kernel(
    const float* __restrict__ A, const float* __restrict__ w,
    const float* __restrict__ bias, float* __restrict__ y) {
  __shared__ float As[32][68];
  __shared__ float Ws[32][68];
  const int t = threadIdx.x;
  const int r0 = blockIdx.x * 64;
  const int o0 = blockIdx.y * 64;
  const int tr = t >> 4, tc = t & 15;
  float acc[4][4] = {};
  for (int i0 = 0; i0 < DMODEL; i0 += 32) {
    #pragma unroll
    for (int u = 0; u < 8; ++u) {
      int idx = t + u * 256;
      int k = idx & 31, rr = idx >> 5;
      As[k][rr] = A[(size_t)(r0 + rr) * DMODEL + i0 + k];
    }
    #pragma unroll
    for (int u = 0; u < 8; ++u) {
      int idx = t + u * 256;
      int k = idx & 31, oo = idx >> 5;
      Ws[k][oo] = w[(size_t)(o0 + oo) * DMODEL + i0 + k];
    }
    __syncthreads();
    #pragma unroll
    for (int k = 0; k < 32; ++k) {
      const float4 av = *(const float4*)&As[k][4 * tr];
      const float4 bv = *(const float4*)&Ws[k][4 * tc];
      float a[4] = {av.x, av.y, av.z, av.w};
      float bb[4] = {bv.x, bv.y, bv.z, bv.w};
      #pragma unroll
      for (int i = 0; i < 4; ++i)
        #pragma unroll
        for (int j = 0; j < 4; ++j)
          acc[i][j] = fmaf(a[i], bb[j], acc[i][j]);
    }
    __syncthreads();
  }
  #pragma unroll
  for (int i = 0; i < 4; ++i) {
    int row = r0 + tr * 4 + i;
    float4 o4;
    float* po = (float*)&o4;
    #pragma unroll
    for (int j = 0; j < 4; ++j) po[j] = acc[i][j] + bias[o0 + tc * 4 + j];
    *(float4*)&y[(size_t)row * DMODEL + (o0 + tc * 4)] = o4;
  }
}

// residual add + LayerNorm, one row per block
__global__ __launch_bounds__(256) void ln_kernel(
    const float* __restrict__ proj, const float* __restrict__ resid,
    const float* __restrict__ gam, const float* __restrict__ bet,
    float* __restrict__ out) {
  __shared__ float red[2][4];
  const int row = blockIdx.x;
  const int t = threadIdx.x;
  const float4* pr = (const float4*)(proj + (size_t)row * DMODEL);
  const float4* rr = (const float4*)(resid + (size_t)row * DMODEL);
  float4 v = pr[t];
  float4 q = rr[t];
  v.x += q.x; v.y += q.y; v.z += q.z; v.w += q.w;
  float s = v.x + v.y + v.z + v.w;
  float s2 = v.x * v.x + v.y * v.y + v.z * v.z + v.w * v.w;
  #pragma unroll
  for (int off = 32; off; off >>= 1) {
    s += __shfl_xor(s, off);
    s2 += __shfl_xor(s2, off);
  }
  const int wave = t >> 6;
  if ((t & 63) == 0) { red[0][wave] = s; red[1][wave] = s2; }
  __syncthreads();
  float S = red[0][0] + red[0][1] + red[0][2] + red[0][3];
  float S2 = red[1][0] + red[1][1] + red[1][2] + red[1][3];
  float mu = S * (1.f / 1024.f);
  float var = S2 * (1.f / 1024.f) - mu * mu;
  float inv = rsqrtf(var + 1e-5f);
  float4 gv = ((const float4*)gam)[t];
  float4 bv = ((const float4*)bet)[t];
  float4 o;
  o.x = (v.x - mu) * inv * gv.x + bv.x;
  o.y = (v.y - mu) * inv * gv.y + bv.y;
  o.z = (v.z - mu) * inv * gv.z + bv.z;
  o.w = (v.w - mu) * inv * gv.w + bv.w;
  ((float4*)out)[(size_t)row * 256 + t] = o;
}

extern "C" void kernel_launch(void* const* d_in, const int* in_sizes, int n_in,
                              void* d_out, int out_size, void* d_ws, size_t ws_size,
                              hipStream_t stream) {
  (void)in_sizes; (void)n_in; (void)out_size; (void)ws_size;
  const float* key   = (const float*)d_in[0];
  const float* value = (const float*)d_in[1];
  const float* query = (const float*)d_in[2];
  const float* wk    = (const float*)d_in[3];
  const float* bk    = (const float*)d_in[4];
  const float* wv    = (const float*)d_in[5];
  const float* bv    = (const float*)d_in[6];
  const float* wq    = (const float*)d_in[7];
  const float* bq    = (const float*)d_in[8];
  const float* wf    = (const float*)d_in[9];
  const float* bf    = (const float*)d_in[10];
  const float* ln_g  = (const float*)d_in[11];
  const float* ln_b  = (const float*)d_in[12];

  float* out  = (float*)d_out;
  float* attn = out + 4194304;
  float* ws   = (float*)d_ws;
  float* Qb    = ws + OFF_Q;
  float* Kb    = ws + OFF_K;
  float* Vb    = ws + OFF_V;
  float* RS    = ws + OFF_RS;
  float* LOGRS = ws + OFF_LOGRS;
  float* VSUM  = ws + OFF_VSUM;
  float* CTX   = ws + OFF_CTX;   // aliases Q (safe: block reads its q rows first)
  float* PROJ  = ws + OFF_PROJ;  // aliases K (dead after attn_main)

  dim3 gg(64, 16);
  conv_gelu_kernel<<<gg, 256, 0, stream>>>(key,   wk, bk, Kb);
  conv_gelu_kernel<<<gg, 256, 0, stream>>>(value, wv, bv, Vb);
  conv_gelu_kernel<<<gg, 256, 0, stream>>>(query, wq, bq, Qb);
  vsum_kernel<<<64, 256, 0, stream>>>(Vb, VSUM);
  attn_main_kernel<<<dim3(64, 32), 256, 0, stream>>>(Qb, Kb, Vb, attn, CTX, RS);
  logrs_kernel<<<256, 256, 0, stream>>>(RS, LOGRS);
  fixup_attn_kernel<<<4096, 256, 0, stream>>>(attn, LOGRS);
  fixup_ctx_kernel<<<4096, 256, 0, stream>>>(CTX, LOGRS, VSUM);
  proj_kernel<<<gg, 256, 0, stream>>>(CTX, wf, bf, PROJ);
  ln_kernel<<<4096, 256, 0, stream>>>(PROJ, query, ln_g, ln_b, out);
}

// Round 5
// 644.071 us; speedup vs baseline: 3.9951x; 3.9951x over previous
//
#include <hip/hip_runtime.h>
#include <math.h>

typedef _Float16 half8 __attribute__((ext_vector_type(8)));
typedef _Float16 half4 __attribute__((ext_vector_type(4)));
typedef float f32x4 __attribute__((ext_vector_type(4)));

#define MFMA16(a, b, c) __builtin_amdgcn_mfma_f32_16x16x32_f16(a, b, c, 0, 0, 0)

__device__ __forceinline__ void gload16(void* lds, const void* g) {
  __builtin_amdgcn_global_load_lds(
      (const __attribute__((address_space(1))) unsigned int*)g,
      (__attribute__((address_space(3))) unsigned int*)lds, 16, 0, 0);
}

// ---------------------------------------------------------------------------
// fp32 -> f16 cast (4 elems/thread)
// ---------------------------------------------------------------------------
__global__ __launch_bounds__(256) void cast4_kernel(
    const float* __restrict__ in, _Float16* __restrict__ out) {
  int i = blockIdx.x * 256 + threadIdx.x;
  float4 v = ((const float4*)in)[i];
  half4 h = {(_Float16)v.x, (_Float16)v.y, (_Float16)v.z, (_Float16)v.w};
  ((half4*)out)[i] = h;
}

// w[o][i][kk] fp32 -> wt[kk][o][i] f16
__global__ __launch_bounds__(256) void castwt_kernel(
    const float* __restrict__ w, _Float16* __restrict__ wt) {
  int idx = blockIdx.x * 256 + threadIdx.x;  // o*1024 + i
  wt[idx]           = (_Float16)w[idx * 3 + 0];
  wt[idx + 1048576] = (_Float16)w[idx * 3 + 1];
  wt[idx + 2097152] = (_Float16)w[idx * 3 + 2];
}

// ---------------------------------------------------------------------------
// f16 MFMA GEMM, 64x128 tile, BK=64, 4 waves (2x2), 16x16x32 frags.
// NTAPS=3: conv (wrap rows, gelu) -> f16 FLAT [R][col]  (reshape is free)
// NTAPS=1: projection -> fp32 [r][o]
// ---------------------------------------------------------------------------
template <int NTAPS, bool GELU>
__global__ __launch_bounds__(256) void gemm16_kernel(
    const _Float16* __restrict__ A, const _Float16* __restrict__ Bw,
    const float* __restrict__ bias, _Float16* __restrict__ outh,
    float* __restrict__ outf) {
  __shared__ _Float16 As[64 * 64];    // 8 KB
  __shared__ _Float16 Bs[128 * 64];   // 16 KB
  const int t = threadIdx.x;
  const int w = t >> 6, l = t & 63;
  const int lr = l & 15, lg = l >> 4;
  const int r0 = blockIdx.x * 64, o0 = blockIdx.y * 128;
  const int l0 = r0 & 1023;
  const int wr = (w >> 1) * 32, wc = (w & 1) * 64;
  f32x4 acc[2][4];
  #pragma unroll
  for (int q = 0; q < 2; ++q)
    #pragma unroll
    for (int n = 0; n < 4; ++n) acc[q][n] = (f32x4){0.f, 0.f, 0.f, 0.f};

  const _Float16* Ab = (NTAPS == 3) ? (A + (size_t)(r0 >> 10) * 1048576) : A;

  for (int kk = 0; kk < NTAPS; ++kk) {
    const _Float16* Bb = Bw + (size_t)kk * 1048576;
    for (int i0 = 0; i0 < 1024; i0 += 64) {
      #pragma unroll
      for (int c = 0; c < 2; ++c) {  // A tile: 64 rows x 64 halves
        const int idx = c * 256 + t;
        const int row = idx >> 3, c8 = (idx & 7) * 8;
        const _Float16* asrc;
        if (NTAPS == 3) {
          int ll = (l0 + row + kk - 2) & 1023;  // wrap pad
          asrc = Ab + (size_t)ll * 1024 + i0 + c8;
        } else {
          asrc = Ab + (size_t)(r0 + row) * 1024 + i0 + c8;
        }
        gload16((char*)As + c * 4096 + w * 1024, asrc);
      }
      #pragma unroll
      for (int c = 0; c < 4; ++c) {  // B tile: 128 rows x 64 halves
        const int idx = c * 256 + t;
        const int row = idx >> 3, c8 = (idx & 7) * 8;
        gload16((char*)Bs + c * 4096 + w * 1024,
                Bb + (size_t)(o0 + row) * 1024 + i0 + c8);
      }
      __syncthreads();
      half8 af[2][2];
      #pragma unroll
      for (int q = 0; q < 2; ++q)
        #pragma unroll
        for (int f = 0; f < 2; ++f)
          af[q][f] = *(const half8*)&As[(wr + q * 16 + lr) * 64 + f * 32 + lg * 8];
      #pragma unroll
      for (int n = 0; n < 4; ++n) {
        half8 bf0 = *(const half8*)&Bs[(wc + n * 16 + lr) * 64 + lg * 8];
        half8 bf1 = *(const half8*)&Bs[(wc + n * 16 + lr) * 64 + 32 + lg * 8];
        #pragma unroll
        for (int q = 0; q < 2; ++q) {
          acc[q][n] = MFMA16(af[q][0], bf0, acc[q][n]);
          acc[q][n] = MFMA16(af[q][1], bf1, acc[q][n]);
        }
      }
      __syncthreads();
    }
  }
  #pragma unroll
  for (int q = 0; q < 2; ++q) {
    const int rowb = r0 + wr + q * 16 + lg * 4;
    #pragma unroll
    for (int n = 0; n < 4; ++n) {
      const int col = o0 + wc + n * 16 + lr;
      const float bi = bias[col];
      #pragma unroll
      for (int rr = 0; rr < 4; ++rr) {
        float v = acc[q][n][rr] + bi;
        if (GELU) {
          v = 0.5f * v * (1.f + erff(v * 0.70710678118654752440f));
          // FLAT layout: the head reshape is a free reinterpretation
          outh[(size_t)(rowb + rr) * 1024 + col] = (_Float16)v;
        } else {
          outf[(size_t)(rowb + rr) * 1024 + col] = v;
        }
      }
    }
  }
}

// ---------------------------------------------------------------------------
// Fused two-pass attention. Block: (p, 64 q-rows), 4 waves (16 rows each).
// Pass 1: S = Q K^T (MFMA), rowsum(max(0.5S, 0.1)).
// Pass 2: recompute S, write attn = log(c) - log(rowsum) fp32, stage f16 P,
//         PV MFMA -> ctx f16 FLAT [p*65536 + row*64 + dd].
// K/Q LDS rows are 128 B -> XOR-swizzled (G4). V transposed+swizzled in LDS.
// ---------------------------------------------------------------------------
__global__ __launch_bounds__(256) void attn_kernel(
    const _Float16* __restrict__ Qh, const _Float16* __restrict__ Kh,
    const _Float16* __restrict__ Vh, float* __restrict__ attn,
    _Float16* __restrict__ ctx) {
  __shared__ _Float16 Qs[4096];       // 64x64 swizzled, 8 KB
  __shared__ _Float16 Ks[4096];       // 64x64 swizzled
  __shared__ _Float16 VT[4096];       // [dd][j] transposed, swizzled
  __shared__ _Float16 Ps[64 * 72];    // [qrow][j] padded (stride 144 B)
  const int t = threadIdx.x, w = t >> 6, l = t & 63;
  const int lr = l & 15, lg = l >> 4;
  const int p = blockIdx.x;
  const int q0 = blockIdx.y * 64;
  const _Float16* Qp = Qh + (size_t)p * 65536;
  const _Float16* Kp = Kh + (size_t)p * 65536;
  const _Float16* Vp = Vh + (size_t)p * 65536;

  // stage Q tile (swizzled: LDS byte X holds global byte row*128 + ((X&127)^sw))
  #pragma unroll
  for (int c = 0; c < 2; ++c) {
    const int idx = c * 256 + t;
    const int row = idx >> 3;
    const int bin = ((idx & 7) * 16) ^ ((row & 7) << 4);
    gload16((char*)Qs + c * 4096 + w * 1024,
            (const char*)Qp + (size_t)(q0 + row) * 128 + bin);
  }
  __syncthreads();
  const int Rq = w * 16 + lr;
  half8 qf[2];
  #pragma unroll
  for (int f = 0; f < 2; ++f)
    qf[f] = *(const half8*)((const char*)Qs + Rq * 128 +
                            ((lg * 16 + f * 64) ^ ((Rq & 7) << 4)));

  // ---- pass 1: rowsums ----
  f32x4 rs = {0.f, 0.f, 0.f, 0.f};
  for (int k0 = 0; k0 < 1024; k0 += 64) {
    #pragma unroll
    for (int c = 0; c < 2; ++c) {
      const int idx = c * 256 + t;
      const int row = idx >> 3;
      const int bin = ((idx & 7) * 16) ^ ((row & 7) << 4);
      gload16((char*)Ks + c * 4096 + w * 1024,
              (const char*)Kp + (size_t)(k0 + row) * 128 + bin);
    }
    __syncthreads();
    #pragma unroll
    for (int kj = 0; kj < 4; ++kj) {
      const int Rk = kj * 16 + lr;
      f32x4 s = {0.f, 0.f, 0.f, 0.f};
      #pragma unroll
      for (int f = 0; f < 2; ++f) {
        half8 kf = *(const half8*)((const char*)Ks + Rk * 128 +
                                   ((lg * 16 + f * 64) ^ ((Rk & 7) << 4)));
        s = MFMA16(qf[f], kf, s);
      }
      #pragma unroll
      for (int rr = 0; rr < 4; ++rr) rs[rr] += fmaxf(0.5f * s[rr], 0.1f);
    }
    __syncthreads();
  }
  #pragma unroll
  for (int m = 1; m < 16; m <<= 1) {
    #pragma unroll
    for (int rr = 0; rr < 4; ++rr) rs[rr] += __shfl_xor(rs[rr], m);
  }
  float lrs_[4];
  #pragma unroll
  for (int rr = 0; rr < 4; ++rr) lrs_[rr] = logf(rs[rr]);

  // ---- pass 2: attn write + PV ----
  float* ao = attn + (size_t)p * 1048576 + (size_t)q0 * 1024;
  f32x4 cacc[4];
  #pragma unroll
  for (int n = 0; n < 4; ++n) cacc[n] = (f32x4){0.f, 0.f, 0.f, 0.f};

  for (int k0 = 0; k0 < 1024; k0 += 64) {
    #pragma unroll
    for (int c = 0; c < 2; ++c) {
      const int idx = c * 256 + t;
      const int row = idx >> 3;
      const int bin = ((idx & 7) * 16) ^ ((row & 7) << 4);
      gload16((char*)Ks + c * 4096 + w * 1024,
              (const char*)Kp + (size_t)(k0 + row) * 128 + bin);
    }
    // V transpose into VT[dd][j] (swizzled), b64 writes, coalesced reads
    #pragma unroll
    for (int u = 0; u < 4; ++u) {
      const int jg = u * 4 + w;  // 0..15
      half4 vv;
      #pragma unroll
      for (int jj = 0; jj < 4; ++jj)
        vv[jj] = Vp[(size_t)(k0 + jg * 4 + jj) * 64 + l];
      *(half4*)((char*)VT + l * 128 + ((jg * 8) ^ ((l & 7) << 4))) = vv;
    }
    __syncthreads();
    #pragma unroll
    for (int kj = 0; kj < 4; ++kj) {
      const int Rk = kj * 16 + lr;
      f32x4 s = {0.f, 0.f, 0.f, 0.f};
      #pragma unroll
      for (int f = 0; f < 2; ++f) {
        half8 kf = *(const half8*)((const char*)Ks + Rk * 128 +
                                   ((lg * 16 + f * 64) ^ ((Rk & 7) << 4)));
        s = MFMA16(qf[f], kf, s);
      }
      #pragma unroll
      for (int rr = 0; rr < 4; ++rr) {
        const float c_ = fmaxf(0.5f * s[rr], 0.1f);
        const float lc = logf(c_) - lrs_[rr];
        const int row = w * 16 + lg * 4 + rr;
        ao[(size_t)row * 1024 + k0 + kj * 16 + lr] = lc;
        Ps[row * 72 + kj * 16 + lr] = (_Float16)lc;
      }
    }
    __syncthreads();
    #pragma unroll
    for (int ks = 0; ks < 2; ++ks) {
      half8 pf = *(const half8*)&Ps[Rq * 72 + ks * 32 + lg * 8];
      #pragma unroll
      for (int nj = 0; nj < 4; ++nj) {
        const int dd = nj * 16 + lr;
        half8 vf = *(const half8*)((const char*)VT + dd * 128 +
                                   ((ks * 64 + lg * 16) ^ ((dd & 7) << 4)));
        cacc[nj] = MFMA16(pf, vf, cacc[nj]);
      }
    }
    __syncthreads();
  }
  // FLAT ctx store: head reshape back to (4096,1024) is a reinterpretation
  #pragma unroll
  for (int nj = 0; nj < 4; ++nj) {
    const int dd = nj * 16 + lr;
    #pragma unroll
    for (int rr = 0; rr < 4; ++rr) {
      const int row = q0 + w * 16 + lg * 4 + rr;
      ctx[(size_t)p * 65536 + (size_t)row * 64 + dd] = (_Float16)cacc[nj][rr];
    }
  }
}

// ---------------------------------------------------------------------------
// residual add + LayerNorm, one row per block
// ---------------------------------------------------------------------------
__global__ __launch_bounds__(256) void ln_kernel(
    const float* __restrict__ proj, const float* __restrict__ resid,
    const float* __restrict__ gam, const float* __restrict__ bet,
    float* __restrict__ out) {
  __shared__ float red[2][4];
  const int row = blockIdx.x;
  const int t = threadIdx.x;
  float4 v = ((const float4*)(proj + (size_t)row * 1024))[t];
  float4 q = ((const float4*)(resid + (size_t)row * 1024))[t];
  v.x += q.x; v.y += q.y; v.z += q.z; v.w += q.w;
  float s = v.x + v.y + v.z + v.w;
  float s2 = v.x * v.x + v.y * v.y + v.z * v.z + v.w * v.w;
  #pragma unroll
  for (int off = 32; off; off >>= 1) {
    s += __shfl_xor(s, off);
    s2 += __shfl_xor(s2, off);
  }
  const int wave = t >> 6;
  if ((t & 63) == 0) { red[0][wave] = s; red[1][wave] = s2; }
  __syncthreads();
  float S = red[0][0] + red[0][1] + red[0][2] + red[0][3];
  float S2 = red[1][0] + red[1][1] + red[1][2] + red[1][3];
  float mu = S * (1.f / 1024.f);
  float var = S2 * (1.f / 1024.f) - mu * mu;
  float inv = rsqrtf(var + 1e-5f);
  float4 gv = ((const float4*)gam)[t];
  float4 bv = ((const float4*)bet)[t];
  float4 o;
  o.x = (v.x - mu) * inv * gv.x + bv.x;
  o.y = (v.y - mu) * inv * gv.y + bv.y;
  o.z = (v.z - mu) * inv * gv.z + bv.z;
  o.w = (v.w - mu) * inv * gv.w + bv.w;
  ((float4*)out)[(size_t)row * 256 + t] = o;
}

extern "C" void kernel_launch(void* const* d_in, const int* in_sizes, int n_in,
                              void* d_out, int out_size, void* d_ws, size_t ws_size,
                              hipStream_t stream) {
  (void)in_sizes; (void)n_in; (void)out_size; (void)ws_size;
  const float* key   = (const float*)d_in[0];
  const float* value = (const float*)d_in[1];
  const float* query = (const float*)d_in[2];
  const float* wk    = (const float*)d_in[3];
  const float* bk    = (const float*)d_in[4];
  const float* wv    = (const float*)d_in[5];
  const float* bv    = (const float*)d_in[6];
  const float* wq    = (const float*)d_in[7];
  const float* bq    = (const float*)d_in[8];
  const float* wf    = (const float*)d_in[9];
  const float* bf    = (const float*)d_in[10];
  const float* ln_g  = (const float*)d_in[11];
  const float* ln_b  = (const float*)d_in[12];

  float* out  = (float*)d_out;
  float* attn = out + 4194304;

  char* ws = (char*)d_ws;
  _Float16* XB   = (_Float16*)(ws + (0u << 20));   // 8 MB (reused per conv)
  _Float16* WT   = (_Float16*)(ws + (8u << 20));   // 6 MB (reused per conv)
  _Float16* WFT  = (_Float16*)(ws + (14u << 20));  // 2 MB
  _Float16* QF   = (_Float16*)(ws + (16u << 20));  // 8 MB each
  _Float16* KF   = (_Float16*)(ws + (24u << 20));
  _Float16* VF   = (_Float16*)(ws + (32u << 20));
  _Float16* CTX  = (_Float16*)(ws + (0u << 20));   // aliases XB (dead by then)
  float*    PROJ = (float*)   (ws + (24u << 20));  // aliases KF+VF (dead)

  dim3 gg(64, 8);
  cast4_kernel<<<1024, 256, 0, stream>>>(wf, WFT);

  cast4_kernel<<<4096, 256, 0, stream>>>(key, XB);
  castwt_kernel<<<4096, 256, 0, stream>>>(wk, WT);
  gemm16_kernel<3, true><<<gg, 256, 0, stream>>>(XB, WT, bk, KF, nullptr);

  cast4_kernel<<<4096, 256, 0, stream>>>(value, XB);
  castwt_kernel<<<4096, 256, 0, stream>>>(wv, WT);
  gemm16_kernel<3, true><<<gg, 256, 0, stream>>>(XB, WT, bv, VF, nullptr);

  cast4_kernel<<<4096, 256, 0, stream>>>(query, XB);
  castwt_kernel<<<4096, 256, 0, stream>>>(wq, WT);
  gemm16_kernel<3, true><<<gg, 256, 0, stream>>>(XB, WT, bq, QF, nullptr);

  attn_kernel<<<dim3(64, 16), 256, 0, stream>>>(QF, KF, VF, attn, CTX);

  gemm16_kernel<1, false><<<gg, 256, 0, stream>>>(CTX, WFT, bf, nullptr, PROJ);
  ln_kernel<<<4096, 256, 0, stream>>>(PROJ, query, ln_g, ln_b, out);
}

// Round 6
// 555.782 us; speedup vs baseline: 4.6298x; 1.1589x over previous
//
#include <hip/hip_runtime.h>
#include <math.h>

typedef _Float16 half8 __attribute__((ext_vector_type(8)));
typedef _Float16 half4 __attribute__((ext_vector_type(4)));
typedef float f32x4 __attribute__((ext_vector_type(4)));

#define MFMA16(a, b, c) __builtin_amdgcn_mfma_f32_16x16x32_f16(a, b, c, 0, 0, 0)

__device__ __forceinline__ void gload16(void* lds, const void* g) {
  __builtin_amdgcn_global_load_lds(
      (const __attribute__((address_space(1))) unsigned int*)g,
      (__attribute__((address_space(3))) unsigned int*)lds, 16, 0, 0);
}

// ---------------------------------------------------------------------------
// fp32 -> f16 casts. One launch for wf; one for {key,value,query};
// one for {wk,wv,wq} (tap-major transpose).
// ---------------------------------------------------------------------------
__global__ __launch_bounds__(256) void cast4_kernel(
    const float* __restrict__ in, _Float16* __restrict__ out) {
  int i = blockIdx.x * 256 + threadIdx.x;
  float4 v = ((const float4*)in)[i];
  half4 h = {(_Float16)v.x, (_Float16)v.y, (_Float16)v.z, (_Float16)v.w};
  ((half4*)out)[i] = h;
}

__global__ __launch_bounds__(256) void cast4x3_kernel(
    const float* __restrict__ a, const float* __restrict__ b,
    const float* __restrict__ c, _Float16* __restrict__ out) {
  const int z = blockIdx.y;
  const float* src = (z == 0) ? a : ((z == 1) ? b : c);
  int i = blockIdx.x * 256 + threadIdx.x;
  float4 v = ((const float4*)src)[i];
  half4 h = {(_Float16)v.x, (_Float16)v.y, (_Float16)v.z, (_Float16)v.w};
  ((half4*)(out + (size_t)z * 4194304))[i] = h;
}

// w[o][i][kk] fp32 -> wt[kk][o][i] f16, for 3 weight tensors
__global__ __launch_bounds__(256) void castwt3_kernel(
    const float* __restrict__ wk, const float* __restrict__ wv,
    const float* __restrict__ wq, _Float16* __restrict__ wt) {
  const int z = blockIdx.y;
  const float* w = (z == 0) ? wk : ((z == 1) ? wv : wq);
  _Float16* o = wt + (size_t)z * 3145728;
  int idx = blockIdx.x * 256 + threadIdx.x;  // o*1024 + i
  o[idx]           = (_Float16)w[idx * 3 + 0];
  o[idx + 1048576] = (_Float16)w[idx * 3 + 1];
  o[idx + 2097152] = (_Float16)w[idx * 3 + 2];
}

// ---------------------------------------------------------------------------
// f16 MFMA GEMM body, 64x128 tile, BK=64, 4 waves (2x2), 16x16x32 frags.
// LDS tiles XOR-swizzled (T2/G21): source chunk ^= row&7 (gload_lds dest stays
// linear), reads XOR the same pattern -> 16-way bank conflict -> 2-way (free).
// NTAPS=3: conv (wrap rows, gelu) -> f16 FLAT [R][col]
// NTAPS=1: projection -> fp32 [r][o]
// ---------------------------------------------------------------------------
template <int NTAPS, bool GELU>
__device__ __forceinline__ void gemm16_body(
    const _Float16* __restrict__ A, const _Float16* __restrict__ Bw,
    const float* __restrict__ bias, _Float16* __restrict__ outh,
    float* __restrict__ outf) {
  __shared__ _Float16 As[64 * 64];    // 8 KB  (64 rows x 128 B, swizzled)
  __shared__ _Float16 Bs[128 * 64];   // 16 KB (128 rows x 128 B, swizzled)
  const int t = threadIdx.x;
  const int w = t >> 6, l = t & 63;
  const int lr = l & 15, lg = l >> 4;
  const int r0 = blockIdx.x * 64, o0 = blockIdx.y * 128;
  const int l0 = r0 & 1023;
  const int wr = (w >> 1) * 32, wc = (w & 1) * 64;
  f32x4 acc[2][4];
  #pragma unroll
  for (int q = 0; q < 2; ++q)
    #pragma unroll
    for (int n = 0; n < 4; ++n) acc[q][n] = (f32x4){0.f, 0.f, 0.f, 0.f};

  const _Float16* Ab = (NTAPS == 3) ? (A + (size_t)(r0 >> 10) * 1048576) : A;

  for (int kk = 0; kk < NTAPS; ++kk) {
    const _Float16* Bb = Bw + (size_t)kk * 1048576;
    for (int i0 = 0; i0 < 1024; i0 += 64) {
      #pragma unroll
      for (int c = 0; c < 2; ++c) {  // A tile: 64 rows x 64 halves
        const int idx = c * 256 + t;
        const int row = idx >> 3;
        const int cs = ((idx & 7) ^ (row & 7)) * 8;  // swizzled source chunk
        const _Float16* asrc;
        if (NTAPS == 3) {
          int ll = (l0 + row + kk - 2) & 1023;  // wrap pad
          asrc = Ab + (size_t)ll * 1024 + i0 + cs;
        } else {
          asrc = Ab + (size_t)(r0 + row) * 1024 + i0 + cs;
        }
        gload16((char*)As + c * 4096 + w * 1024, asrc);
      }
      #pragma unroll
      for (int c = 0; c < 4; ++c) {  // B tile: 128 rows x 64 halves
        const int idx = c * 256 + t;
        const int row = idx >> 3;
        const int cs = ((idx & 7) ^ (row & 7)) * 8;
        gload16((char*)Bs + c * 4096 + w * 1024,
                Bb + (size_t)(o0 + row) * 1024 + i0 + cs);
      }
      __syncthreads();
      half8 af[2][2];
      #pragma unroll
      for (int q = 0; q < 2; ++q) {
        const int R = wr + q * 16 + lr;
        #pragma unroll
        for (int f = 0; f < 2; ++f)
          af[q][f] = *(const half8*)((const char*)As + R * 128 +
                                     ((f * 64 + lg * 16) ^ ((R & 7) << 4)));
      }
      #pragma unroll
      for (int n = 0; n < 4; ++n) {
        const int Rb = wc + n * 16 + lr;
        half8 bf0 = *(const half8*)((const char*)Bs + Rb * 128 +
                                    ((lg * 16) ^ ((Rb & 7) << 4)));
        half8 bf1 = *(const half8*)((const char*)Bs + Rb * 128 +
                                    ((64 + lg * 16) ^ ((Rb & 7) << 4)));
        #pragma unroll
        for (int q = 0; q < 2; ++q) {
          acc[q][n] = MFMA16(af[q][0], bf0, acc[q][n]);
          acc[q][n] = MFMA16(af[q][1], bf1, acc[q][n]);
        }
      }
      __syncthreads();
    }
  }
  #pragma unroll
  for (int q = 0; q < 2; ++q) {
    const int rowb = r0 + wr + q * 16 + lg * 4;
    #pragma unroll
    for (int n = 0; n < 4; ++n) {
      const int col = o0 + wc + n * 16 + lr;
      const float bi = bias[col];
      #pragma unroll
      for (int rr = 0; rr < 4; ++rr) {
        float v = acc[q][n][rr] + bi;
        if (GELU) {
          v = 0.5f * v * (1.f + erff(v * 0.70710678118654752440f));
          outh[(size_t)(rowb + rr) * 1024 + col] = (_Float16)v;  // FLAT layout
        } else {
          outf[(size_t)(rowb + rr) * 1024 + col] = v;
        }
      }
    }
  }
}

// All three convs in one launch: blockIdx.z selects {key,value,query} set.
__global__ __launch_bounds__(256) void conv3_kernel(
    const _Float16* __restrict__ X3, const _Float16* __restrict__ W3,
    const float* __restrict__ bk, const float* __restrict__ bv,
    const float* __restrict__ bq, _Float16* __restrict__ Ko,
    _Float16* __restrict__ Vo, _Float16* __restrict__ Qo) {
  const int z = blockIdx.z;
  gemm16_body<3, true>(X3 + (size_t)z * 4194304, W3 + (size_t)z * 3145728,
                       (z == 0) ? bk : ((z == 1) ? bv : bq),
                       (z == 0) ? Ko : ((z == 1) ? Vo : Qo), nullptr);
}

__global__ __launch_bounds__(256) void proj_kernel(
    const _Float16* __restrict__ A, const _Float16* __restrict__ Bw,
    const float* __restrict__ bias, float* __restrict__ outf) {
  gemm16_body<1, false>(A, Bw, bias, nullptr, outf);
}

// ---------------------------------------------------------------------------
// Fused two-pass attention. Block: (p, 64 q-rows), 4 waves (16 rows each).
// Pass 1: S = Q K^T (MFMA), rowsum(max(0.5S, 0.1)).
// Pass 2: recompute S, write attn = log(c) - log(rowsum) fp32, stage f16 P,
//         PV MFMA -> ctx f16 FLAT [p*65536 + row*64 + dd].
// K/Q LDS rows are 128 B -> XOR-swizzled. V transposed+swizzled in LDS.
// Ps stride 76 halves (152 B): word-stride 38 == 6 mod 32 -> <=2-way banks.
// ---------------------------------------------------------------------------
__global__ __launch_bounds__(256) void attn_kernel(
    const _Float16* __restrict__ Qh, const _Float16* __restrict__ Kh,
    const _Float16* __restrict__ Vh, float* __restrict__ attn,
    _Float16* __restrict__ ctx) {
  __shared__ _Float16 Qs[4096];       // 64x64 swizzled, 8 KB
  __shared__ _Float16 Ks[4096];       // 64x64 swizzled
  __shared__ _Float16 VT[4096];       // [dd][j] transposed, swizzled
  __shared__ _Float16 Ps[64 * 76];    // [qrow][j], stride 152 B
  const int t = threadIdx.x, w = t >> 6, l = t & 63;
  const int lr = l & 15, lg = l >> 4;
  const int p = blockIdx.x;
  const int q0 = blockIdx.y * 64;
  const _Float16* Qp = Qh + (size_t)p * 65536;
  const _Float16* Kp = Kh + (size_t)p * 65536;
  const _Float16* Vp = Vh + (size_t)p * 65536;

  #pragma unroll
  for (int c = 0; c < 2; ++c) {
    const int idx = c * 256 + t;
    const int row = idx >> 3;
    const int bin = ((idx & 7) * 16) ^ ((row & 7) << 4);
    gload16((char*)Qs + c * 4096 + w * 1024,
            (const char*)Qp + (size_t)(q0 + row) * 128 + bin);
  }
  __syncthreads();
  const int Rq = w * 16 + lr;
  half8 qf[2];
  #pragma unroll
  for (int f = 0; f < 2; ++f)
    qf[f] = *(const half8*)((const char*)Qs + Rq * 128 +
                            ((lg * 16 + f * 64) ^ ((Rq & 7) << 4)));

  // ---- pass 1: rowsums ----
  f32x4 rs = {0.f, 0.f, 0.f, 0.f};
  for (int k0 = 0; k0 < 1024; k0 += 64) {
    #pragma unroll
    for (int c = 0; c < 2; ++c) {
      const int idx = c * 256 + t;
      const int row = idx >> 3;
      const int bin = ((idx & 7) * 16) ^ ((row & 7) << 4);
      gload16((char*)Ks + c * 4096 + w * 1024,
              (const char*)Kp + (size_t)(k0 + row) * 128 + bin);
    }
    __syncthreads();
    #pragma unroll
    for (int kj = 0; kj < 4; ++kj) {
      const int Rk = kj * 16 + lr;
      f32x4 s = {0.f, 0.f, 0.f, 0.f};
      #pragma unroll
      for (int f = 0; f < 2; ++f) {
        half8 kf = *(const half8*)((const char*)Ks + Rk * 128 +
                                   ((lg * 16 + f * 64) ^ ((Rk & 7) << 4)));
        s = MFMA16(qf[f], kf, s);
      }
      #pragma unroll
      for (int rr = 0; rr < 4; ++rr) rs[rr] += fmaxf(0.5f * s[rr], 0.1f);
    }
    __syncthreads();
  }
  #pragma unroll
  for (int m = 1; m < 16; m <<= 1) {
    #pragma unroll
    for (int rr = 0; rr < 4; ++rr) rs[rr] += __shfl_xor(rs[rr], m);
  }
  float lrs_[4];
  #pragma unroll
  for (int rr = 0; rr < 4; ++rr) lrs_[rr] = logf(rs[rr]);

  // ---- pass 2: attn write + PV ----
  float* ao = attn + (size_t)p * 1048576 + (size_t)q0 * 1024;
  f32x4 cacc[4];
  #pragma unroll
  for (int n = 0; n < 4; ++n) cacc[n] = (f32x4){0.f, 0.f, 0.f, 0.f};

  for (int k0 = 0; k0 < 1024; k0 += 64) {
    #pragma unroll
    for (int c = 0; c < 2; ++c) {
      const int idx = c * 256 + t;
      const int row = idx >> 3;
      const int bin = ((idx & 7) * 16) ^ ((row & 7) << 4);
      gload16((char*)Ks + c * 4096 + w * 1024,
              (const char*)Kp + (size_t)(k0 + row) * 128 + bin);
    }
    // V transpose into VT[dd][j] (swizzled)
    #pragma unroll
    for (int u = 0; u < 4; ++u) {
      const int jg = u * 4 + w;  // 0..15
      half4 vv;
      #pragma unroll
      for (int jj = 0; jj < 4; ++jj)
        vv[jj] = Vp[(size_t)(k0 + jg * 4 + jj) * 64 + l];
      *(half4*)((char*)VT + l * 128 + ((jg * 8) ^ ((l & 7) << 4))) = vv;
    }
    __syncthreads();
    #pragma unroll
    for (int kj = 0; kj < 4; ++kj) {
      const int Rk = kj * 16 + lr;
      f32x4 s = {0.f, 0.f, 0.f, 0.f};
      #pragma unroll
      for (int f = 0; f < 2; ++f) {
        half8 kf = *(const half8*)((const char*)Ks + Rk * 128 +
                                   ((lg * 16 + f * 64) ^ ((Rk & 7) << 4)));
        s = MFMA16(qf[f], kf, s);
      }
      #pragma unroll
      for (int rr = 0; rr < 4; ++rr) {
        const float c_ = fmaxf(0.5f * s[rr], 0.1f);
        const float lc = logf(c_) - lrs_[rr];
        const int row = w * 16 + lg * 4 + rr;
        ao[(size_t)row * 1024 + k0 + kj * 16 + lr] = lc;
        Ps[row * 76 + kj * 16 + lr] = (_Float16)lc;
      }
    }
    __syncthreads();
    #pragma unroll
    for (int ks = 0; ks < 2; ++ks) {
      half8 pf = *(const half8*)&Ps[Rq * 76 + ks * 32 + lg * 8];
      #pragma unroll
      for (int nj = 0; nj < 4; ++nj) {
        const int dd = nj * 16 + lr;
        half8 vf = *(const half8*)((const char*)VT + dd * 128 +
                                   ((ks * 64 + lg * 16) ^ ((dd & 7) << 4)));
        cacc[nj] = MFMA16(pf, vf, cacc[nj]);
      }
    }
    __syncthreads();
  }
  // FLAT ctx store
  #pragma unroll
  for (int nj = 0; nj < 4; ++nj) {
    const int dd = nj * 16 + lr;
    #pragma unroll
    for (int rr = 0; rr < 4; ++rr) {
      const int row = q0 + w * 16 + lg * 4 + rr;
      ctx[(size_t)p * 65536 + (size_t)row * 64 + dd] = (_Float16)cacc[nj][rr];
    }
  }
}

// ---------------------------------------------------------------------------
// residual add + LayerNorm, one row per block
// ---------------------------------------------------------------------------
__global__ __launch_bounds__(256) void ln_kernel(
    const float* __restrict__ proj, const float* __restrict__ resid,
    const float* __restrict__ gam, const float* __restrict__ bet,
    float* __restrict__ out) {
  __shared__ float red[2][4];
  const int row = blockIdx.x;
  const int t = threadIdx.x;
  float4 v = ((const float4*)(proj + (size_t)row * 1024))[t];
  float4 q = ((const float4*)(resid + (size_t)row * 1024))[t];
  v.x += q.x; v.y += q.y; v.z += q.z; v.w += q.w;
  float s = v.x + v.y + v.z + v.w;
  float s2 = v.x * v.x + v.y * v.y + v.z * v.z + v.w * v.w;
  #pragma unroll
  for (int off = 32; off; off >>= 1) {
    s += __shfl_xor(s, off);
    s2 += __shfl_xor(s2, off);
  }
  const int wave = t >> 6;
  if ((t & 63) == 0) { red[0][wave] = s; red[1][wave] = s2; }
  __syncthreads();
  float S = red[0][0] + red[0][1] + red[0][2] + red[0][3];
  float S2 = red[1][0] + red[1][1] + red[1][2] + red[1][3];
  float mu = S * (1.f / 1024.f);
  float var = S2 * (1.f / 1024.f) - mu * mu;
  float inv = rsqrtf(var + 1e-5f);
  float4 gv = ((const float4*)gam)[t];
  float4 bv = ((const float4*)bet)[t];
  float4 o;
  o.x = (v.x - mu) * inv * gv.x + bv.x;
  o.y = (v.y - mu) * inv * gv.y + bv.y;
  o.z = (v.z - mu) * inv * gv.z + bv.z;
  o.w = (v.w - mu) * inv * gv.w + bv.w;
  ((float4*)out)[(size_t)row * 256 + t] = o;
}

extern "C" void kernel_launch(void* const* d_in, const int* in_sizes, int n_in,
                              void* d_out, int out_size, void* d_ws, size_t ws_size,
                              hipStream_t stream) {
  (void)in_sizes; (void)n_in; (void)out_size; (void)ws_size;
  const float* key   = (const float*)d_in[0];
  const float* value = (const float*)d_in[1];
  const float* query = (const float*)d_in[2];
  const float* wk    = (const float*)d_in[3];
  const float* bk    = (const float*)d_in[4];
  const float* wv    = (const float*)d_in[5];
  const float* bv    = (const float*)d_in[6];
  const float* wq    = (const float*)d_in[7];
  const float* bq    = (const float*)d_in[8];
  const float* wf    = (const float*)d_in[9];
  const float* bf    = (const float*)d_in[10];
  const float* ln_g  = (const float*)d_in[11];
  const float* ln_b  = (const float*)d_in[12];

  float* out  = (float*)d_out;
  float* attn = out + 4194304;

  char* ws = (char*)d_ws;
  _Float16* XB3  = (_Float16*)(ws + ( 0ull << 20));  // 3 x 8 MB (k,v,q f16)
  _Float16* WT3  = (_Float16*)(ws + (24ull << 20));  // 3 x 6 MB (tap-major)
  _Float16* WFT  = (_Float16*)(ws + (42ull << 20));  // 2 MB
  _Float16* KF   = (_Float16*)(ws + (44ull << 20));  // 8 MB each
  _Float16* VF   = (_Float16*)(ws + (52ull << 20));
  _Float16* QF   = (_Float16*)(ws + (60ull << 20));
  _Float16* CTX  = (_Float16*)(ws + (68ull << 20));  // 8 MB
  float*    PROJ = (float*)   (ws + (76ull << 20));  // 16 MB fp32

  cast4_kernel<<<1024, 256, 0, stream>>>(wf, WFT);
  cast4x3_kernel<<<dim3(4096, 3), 256, 0, stream>>>(key, value, query, XB3);
  castwt3_kernel<<<dim3(4096, 3), 256, 0, stream>>>(wk, wv, wq, WT3);

  conv3_kernel<<<dim3(64, 8, 3), 256, 0, stream>>>(XB3, WT3, bk, bv, bq,
                                                   KF, VF, QF);

  attn_kernel<<<dim3(64, 16), 256, 0, stream>>>(QF, KF, VF, attn, CTX);

  proj_kernel<<<dim3(64, 8), 256, 0, stream>>>(CTX, WFT, bf, PROJ);
  ln_kernel<<<4096, 256, 0, stream>>>(PROJ, query, ln_g, ln_b, out);
}